// Round 3
// baseline (241.908 us; speedup 1.0000x reference)
//
#include <hip/hip_runtime.h>
#include <math.h>

#define NSPEC 7
#define NMOL 1024
#define APM 48
#define NATOMS (NMOL * APM)   // 49152
#define FDIM 384

typedef unsigned short u16;
typedef unsigned int u32;
typedef unsigned long long u64;
typedef __attribute__((ext_vector_type(8))) short short8;
typedef __attribute__((ext_vector_type(4))) float floatx4;

// Packed-weight geometry: [s][ntile][kg][lane(64)][8] bf16, frag = 16B/lane.
#define W1_ELEMS_PER_S (16 * 12 * 64 * 8)   // 98304
#define W2_ELEMS_PER_S (12 * 8 * 64 * 8)    // 49152
#define W3_ELEMS_PER_S (10 * 6 * 64 * 8)    // 30720

#define BUCKET_BLOCKS (NATOMS / 256)        // 192
#define PACK1_BLOCKS (NSPEC * 16)           // 112 (one block per (s, ntile))
#define PACK2_BLOCKS (NSPEC * 12)           // 84
#define PACK3_BLOCKS (NSPEC * 10)           // 70
#define PREP_BLOCKS (BUCKET_BLOCKS + PACK1_BLOCKS + PACK2_BLOCKS + PACK3_BLOCKS)

// Block = 32 atoms, 2 waves split the NEURON-TILE dim (wave w does tiles
// t ≡ w mod 2). Weight traffic per atom unchanged; 2× waves for latency hiding.
// Σ_s ceil(cnt_s/32) ≤ 49152/32 + 6 = 1542; 1543 is safe.
#define MLP_BLOCKS 1543

// ws layout (bytes): g_cnt[8] @0, w1p @32, w2p, w3p, bucket u16[7*NATOMS]. ~3.2 MB.
#define WS_W1_OFF 32
#define WS_W2_OFF (WS_W1_OFF + 1376256)
#define WS_W3_OFF (WS_W2_OFF + 688128)
#define WS_BKT_OFF (WS_W3_OFF + 430080)

#define STA 264   // bufA row stride in u16 (for 256-wide; 132 dw ≡ 4 mod 32: structurally conflict-free)
#define STB 200   // bufB row stride in u16 (for 192-wide; 100 dw ≡ 4 mod 32: same form)

__device__ __forceinline__ float celu01(float x) {
    // celu(x,0.1) = x>0 ? x : 0.1*(exp(10x)-1); __expf = native v_exp (~6 VALU).
    float e = fmaf(0.1f, __expf(x * 10.0f), -0.1f);
    return x > 0.0f ? x : e;
}

__device__ __forceinline__ u16 bfr(float f) {  // fp32 -> bf16 RNE
    u32 u = __float_as_uint(f);
    u += 0x7fffu + ((u >> 16) & 1u);
    return (u16)(u >> 16);
}

__device__ __forceinline__ float bf2f(short s) {
    return __uint_as_float(((u32)(u16)s) << 16);
}

union U8 { short8 v; u16 u[8]; };
union U4 { u64 ll; u16 u[4]; };

// ---------------- prep: bucket + d_out zero + COALESCED weight pack ----------------
template <int KGS, int NTILES>
__device__ __forceinline__ void pack_tile(const float* __restrict__ W,
                                          u16* __restrict__ dst,
                                          int s, int t2, u16* lds) {
    const int K = KGS * 32;
    const int K4 = K / 4;                  // compile-time -> magic div
    int t = threadIdx.x;
    const float* wbase = W + ((size_t)(s * NTILES + t2) * 16) * K;
    for (int i = t; i < 16 * K4; i += 256) {
        int r = i / K4, c = i % K4;
        float4 v = ((const float4*)(wbase + (size_t)r * K))[c];
        u16* d = lds + r * K + c * 4;
        d[0] = bfr(v.x); d[1] = bfr(v.y); d[2] = bfr(v.z); d[3] = bfr(v.w);
    }
    __syncthreads();
    int w = t >> 6, lane = t & 63;
    int n = lane & 15, ks = lane >> 4;
    for (int kg = w; kg < KGS; kg += 4) {
        short8 v = *reinterpret_cast<const short8*>(lds + n * K + kg * 32 + ks * 8);
        *reinterpret_cast<short8*>(
            dst + (((size_t)(s * NTILES + t2) * KGS + kg) * 64 + lane) * 8) = v;
    }
}

__global__ void prep_kernel(const int* __restrict__ species,
                            int* __restrict__ g_cnt, u16* __restrict__ bucket,
                            const float* __restrict__ W1, const float* __restrict__ W2,
                            const float* __restrict__ W3,
                            u16* __restrict__ w1p, u16* __restrict__ w2p,
                            u16* __restrict__ w3p, float* __restrict__ out) {
    __shared__ u16 lds[16 * 384];
    __shared__ int l_cnt[NSPEC];
    __shared__ int l_base[NSPEC];
    int t = threadIdx.x;
    int bx = blockIdx.x;
    if (bx < BUCKET_BLOCKS) {
        if (bx == 0) {  // zero d_out (1024 floats); mlp runs strictly after us
            float4 z = {0.f, 0.f, 0.f, 0.f};
            ((float4*)out)[t] = z;
        }
        if (t < NSPEC) l_cnt[t] = 0;
        __syncthreads();
        int i = bx * 256 + t;
        int s = species[i];
        int lpos = atomicAdd(&l_cnt[s], 1);
        __syncthreads();
        if (t < NSPEC) l_base[t] = atomicAdd(&g_cnt[t], l_cnt[t]);
        __syncthreads();
        bucket[s * NATOMS + l_base[s] + lpos] = (u16)i;
    } else if (bx < BUCKET_BLOCKS + PACK1_BLOCKS) {
        int pid = bx - BUCKET_BLOCKS;
        pack_tile<12, 16>(W1, w1p, pid / 16, pid % 16, lds);
    } else if (bx < BUCKET_BLOCKS + PACK1_BLOCKS + PACK2_BLOCKS) {
        int pid = bx - (BUCKET_BLOCKS + PACK1_BLOCKS);
        pack_tile<8, 12>(W2, w2p, pid / 12, pid % 12, lds);
    } else {
        int pid = bx - (BUCKET_BLOCKS + PACK1_BLOCKS + PACK2_BLOCKS);
        pack_tile<6, 10>(W3, w3p, pid / 10, pid % 10, lds);
    }
}

// ---------------- MFMA layer: tile-split across the block's 2 waves ----------------
// Wave w computes tiles t = 2*i + w. Weights as MFMA A-operand → D rows =
// neurons: each lane's 4 accs are 4 consecutive neurons of one atom → one
// ds_write_b64 per acc + float4 bias load.
template <int KGS, int NT, int NBUF, int OST>
__device__ __forceinline__ void run_layer(const short8* af0, const short8* af1,
                                          const u16* __restrict__ wsp,   // pre-offset
                                          const float* __restrict__ bias, // pre-offset
                                          u16* __restrict__ outbuf, int lane, int w) {
    const int NTL = NT / 2;                 // own tiles per wave
    const int nl = lane & 15, kg4 = lane >> 4;
    // pre-offset to this wave's first tile (tile index w); tiles advance by 2
    const u16* wb = wsp + (size_t)lane * 8 + (size_t)w * KGS * 512;
    short8 b[NBUF][KGS];
#pragma unroll
    for (int p = 0; p < NBUF - 1; ++p)
#pragma unroll
        for (int kg = 0; kg < KGS; ++kg)
            b[p][kg] = *reinterpret_cast<const short8*>(wb + ((size_t)p * 2 * KGS + kg) * 512);
#pragma unroll
    for (int i = 0; i < NTL; ++i) {
        int pre = i + NBUF - 1;
        if (pre < NTL) {
            int slot = pre % NBUF;
#pragma unroll
            for (int kg = 0; kg < KGS; ++kg)
                b[slot][kg] = *reinterpret_cast<const short8*>(wb + ((size_t)pre * 2 * KGS + kg) * 512);
        }
        int cur = i % NBUF;
        floatx4 acc0 = {0.f, 0.f, 0.f, 0.f};
        floatx4 acc1 = {0.f, 0.f, 0.f, 0.f};
#pragma unroll
        for (int kg = 0; kg < KGS; ++kg) {
            acc0 = __builtin_amdgcn_mfma_f32_16x16x32_bf16(b[cur][kg], af0[kg], acc0, 0, 0, 0);
            acc1 = __builtin_amdgcn_mfma_f32_16x16x32_bf16(b[cur][kg], af1[kg], acc1, 0, 0, 0);
        }
        int t = 2 * i + w;                  // global tile -> output col block
        floatx4 bn = *reinterpret_cast<const floatx4*>(bias + t * 16 + kg4 * 4);
        U4 p0, p1;
#pragma unroll
        for (int r = 0; r < 4; ++r) {
            p0.u[r] = bfr(celu01(acc0[r] + bn[r]));
            p1.u[r] = bfr(celu01(acc1[r] + bn[r]));
        }
        *reinterpret_cast<u64*>(outbuf + (size_t)nl * OST + t * 16 + kg4 * 4) = p0.ll;
        *reinterpret_cast<u64*>(outbuf + (size_t)(16 + nl) * OST + t * 16 + kg4 * 4) = p1.ll;
    }
}

template <int KGS, int IST>
__device__ __forceinline__ void load_a_lds(const u16* __restrict__ buf,
                                           short8* af0, short8* af1, int lane) {
    int nl = lane & 15, kg4 = lane >> 4;
#pragma unroll
    for (int kg = 0; kg < KGS; ++kg) {
        af0[kg] = *reinterpret_cast<const short8*>(buf + (size_t)nl * IST + kg * 32 + kg4 * 8);
        af1[kg] = *reinterpret_cast<const short8*>(buf + (size_t)(16 + nl) * IST + kg * 32 + kg4 * 8);
    }
}

// Compact 1D grid: block bx maps to (s, chunk) via in-kernel prefix scan of
// g_cnt. Block = 32 atoms, 2 waves tile-split. Ping-pong LDS buffers: only
// write->read barriers needed (3 total), no WAR barriers.
__global__ __launch_bounds__(128, 3) void mlp_kernel(
    const float* __restrict__ aev,
    const u16* __restrict__ w1p, const u16* __restrict__ w2p, const u16* __restrict__ w3p,
    const float* __restrict__ b1, const float* __restrict__ b2, const float* __restrict__ b3,
    const float* __restrict__ W4, const float* __restrict__ b4,
    const int* __restrict__ g_cnt, const u16* __restrict__ bucket,
    float* __restrict__ out) {
    int bx = blockIdx.x;
    int s = -1, chunk = 0;
    {
        int acc = 0;
#pragma unroll
        for (int q = 0; q < NSPEC; ++q) {
            int nb = (g_cnt[q] + 31) >> 5;          // 32 atoms per block
            if (s < 0 && bx < acc + nb) { s = q; chunk = bx - acc; }
            acc += nb;
        }
        if (s < 0) return;                          // bx beyond total work
    }
    int cnt = g_cnt[s];
    int w = threadIdx.x >> 6, lane = threadIdx.x & 63;
    int base = chunk * 32;               // the block's 32 atoms (both waves)

    __shared__ __align__(16) u16 bufA[32 * STA];   // 16896 B (L1 out / L3 out)
    __shared__ __align__(16) u16 bufB[32 * STB];   // 12800 B (L2 out)

    int nl = lane & 15, kg4 = lane >> 4;

    // ---- layer 1: 384 -> 256. A from global fp32 aev (plain loads: aev is
    // L3-resident across iterations — NT loads in R1 forced 105 MB/iter HBM
    // re-streaming and doubled dur; reverted). Both waves load the same A. ----
    short8 af0[12], af1[12];
    {
        int i0 = base + nl;       if (i0 >= cnt) i0 = cnt - 1;
        int i1 = base + 16 + nl;  if (i1 >= cnt) i1 = cnt - 1;
        int a0 = (int)bucket[s * NATOMS + i0];
        int a1 = (int)bucket[s * NATOMS + i1];
        const float* ar0 = aev + (size_t)a0 * FDIM;
        const float* ar1 = aev + (size_t)a1 * FDIM;
#pragma unroll
        for (int kg = 0; kg < 12; ++kg) {
            const float4* p0 = (const float4*)(ar0 + kg * 32 + kg4 * 8);
            const float4* p1 = (const float4*)(ar1 + kg * 32 + kg4 * 8);
            float4 a = p0[0], b = p0[1];
            float4 c = p1[0], d = p1[1];
            U8 x, y;
            x.u[0] = bfr(a.x); x.u[1] = bfr(a.y); x.u[2] = bfr(a.z); x.u[3] = bfr(a.w);
            x.u[4] = bfr(b.x); x.u[5] = bfr(b.y); x.u[6] = bfr(b.z); x.u[7] = bfr(b.w);
            y.u[0] = bfr(c.x); y.u[1] = bfr(c.y); y.u[2] = bfr(c.z); y.u[3] = bfr(c.w);
            y.u[4] = bfr(d.x); y.u[5] = bfr(d.y); y.u[6] = bfr(d.z); y.u[7] = bfr(d.w);
            af0[kg] = x.v;
            af1[kg] = y.v;
        }
    }
    run_layer<12, 16, 2, STA>(af0, af1, w1p + (size_t)s * W1_ELEMS_PER_S, b1 + s * 256, bufA, lane, w);
    __syncthreads();                       // L1 writes (bufA) -> visible

    // ---- layer 2: 256 -> 192, out to bufB (no WAR on bufA) ----
    short8 c0[8], c1[8];
    load_a_lds<8, STA>(bufA, c0, c1, lane);
    run_layer<8, 12, 3, STB>(c0, c1, w2p + (size_t)s * W2_ELEMS_PER_S, b2 + s * 192, bufB, lane, w);
    __syncthreads();                       // L2 writes (bufB) -> visible; also
                                           // orders both waves' bufA reads
                                           // before L3's bufA overwrite

    // ---- layer 3: 192 -> 160, out to bufA ----
    short8 d0[6], d1[6];
    load_a_lds<6, STB>(bufB, d0, d1, lane);
    run_layer<6, 10, 3, STA>(d0, d1, w3p + (size_t)s * W3_ELEMS_PER_S, b3 + s * 160, bufA, lane, w);
    __syncthreads();                       // L3 writes (bufA) -> visible

    // ---- layer 4: 160 -> 1 (fp32 VALU), 2 lanes/atom; wave w does atoms
    // [w*16, w*16+16) with lanes 0..31, + molecule scatter-add ----
    {
        int m = lane >> 1, q = lane & 1;
        if (m < 16) {
            int ai = w * 16 + m;
            const u16* h = bufA + (size_t)ai * STA + q * 80;
            const float* w4s = W4 + s * 160 + q * 80;
            float p = 0.f;
#pragma unroll
            for (int c = 0; c < 10; ++c) {
                short8 hv = *reinterpret_cast<const short8*>(h + c * 8);
                const float4* wp4 = (const float4*)(w4s + c * 8);
                float4 wa = wp4[0], wb = wp4[1];
                p += bf2f(hv[0]) * wa.x + bf2f(hv[1]) * wa.y + bf2f(hv[2]) * wa.z + bf2f(hv[3]) * wa.w;
                p += bf2f(hv[4]) * wb.x + bf2f(hv[5]) * wb.y + bf2f(hv[6]) * wb.z + bf2f(hv[7]) * wb.w;
            }
            p += __shfl_down(p, 1, 2);
            int idx = base + ai;
            if (q == 0 && idx < cnt) {
                int atom = (int)bucket[s * NATOMS + idx];
                atomicAdd(&out[atom / APM], p + b4[s]);
            }
        }
    }
}

extern "C" void kernel_launch(void* const* d_in, const int* in_sizes, int n_in,
                              void* d_out, int out_size, void* d_ws, size_t ws_size,
                              hipStream_t stream) {
    const int* species = (const int*)d_in[0];
    const float* aev = (const float*)d_in[1];
    const float* W1 = (const float*)d_in[2];
    const float* b1 = (const float*)d_in[3];
    const float* W2 = (const float*)d_in[4];
    const float* b2 = (const float*)d_in[5];
    const float* W3 = (const float*)d_in[6];
    const float* b3 = (const float*)d_in[7];
    const float* W4 = (const float*)d_in[8];
    const float* b4 = (const float*)d_in[9];
    float* out = (float*)d_out;

    unsigned char* wsb = (unsigned char*)d_ws;
    int* g_cnt = (int*)wsb;
    u16* w1p = (u16*)(wsb + WS_W1_OFF);
    u16* w2p = (u16*)(wsb + WS_W2_OFF);
    u16* w3p = (u16*)(wsb + WS_W3_OFF);
    u16* bucket = (u16*)(wsb + WS_BKT_OFF);

    hipMemsetAsync(g_cnt, 0, 8 * sizeof(int), stream);

    prep_kernel<<<PREP_BLOCKS, 256, 0, stream>>>(
        species, g_cnt, bucket, W1, W2, W3, w1p, w2p, w3p, out);

    mlp_kernel<<<MLP_BLOCKS, 128, 0, stream>>>(
        aev, w1p, w2p, w3p, b1, b2, b3, W4, b4, g_cnt, bucket, out);
}

// Round 4
// 190.022 us; speedup vs baseline: 1.2730x; 1.2730x over previous
//
#include <hip/hip_runtime.h>
#include <math.h>

#define NSPEC 7
#define NMOL 1024
#define APM 48
#define NATOMS (NMOL * APM)   // 49152
#define FDIM 384

typedef unsigned short u16;
typedef unsigned int u32;
typedef unsigned long long u64;
typedef __attribute__((ext_vector_type(8))) short short8;
typedef __attribute__((ext_vector_type(4))) float floatx4;

// Packed-weight geometry: [s][ntile][kg][lane(64)][8] bf16, frag = 16B/lane.
#define W1_ELEMS_PER_S (16 * 12 * 64 * 8)   // 98304
#define W2_ELEMS_PER_S (12 * 8 * 64 * 8)    // 49152
#define W3_ELEMS_PER_S (10 * 6 * 64 * 8)    // 30720

#define BUCKET_BLOCKS (NATOMS / 256)        // 192
#define PACK1_BLOCKS (NSPEC * 16)           // 112 (one block per (s, ntile))
#define PACK2_BLOCKS (NSPEC * 12)           // 84
#define PACK3_BLOCKS (NSPEC * 10)           // 70
#define PREP_BLOCKS (BUCKET_BLOCKS + PACK1_BLOCKS + PACK2_BLOCKS + PACK3_BLOCKS)

// Block = 32 atoms, 2 waves split the NEURON-TILE dim (wave w does tiles
// t ≡ w mod 2). Σ_s ceil(cnt_s/32) ≤ 49152/32 + 6 = 1542; 1543 is safe.
#define MLP_BLOCKS 1543

// ws layout (bytes): g_cnt[8] @0, w1p @32, w2p, w3p, bucket u16[7*NATOMS]. ~3.2 MB.
#define WS_W1_OFF 32
#define WS_W2_OFF (WS_W1_OFF + 1376256)
#define WS_W3_OFF (WS_W2_OFF + 688128)
#define WS_BKT_OFF (WS_W3_OFF + 430080)

#define BUFST 264   // LDS activation row stride in u16 (132 dw ≡ 4 mod 32: 2-way/free banks)

__device__ __forceinline__ float celu01(float x) {
    // celu(x,0.1) = x>0 ? x : 0.1*(exp(10x)-1); __expf = native v_exp (~6 VALU).
    float e = fmaf(0.1f, __expf(x * 10.0f), -0.1f);
    return x > 0.0f ? x : e;
}

__device__ __forceinline__ u16 bfr(float f) {  // fp32 -> bf16 RNE
    u32 u = __float_as_uint(f);
    u += 0x7fffu + ((u >> 16) & 1u);
    return (u16)(u >> 16);
}

__device__ __forceinline__ float bf2f(short s) {
    return __uint_as_float(((u32)(u16)s) << 16);
}

union U8 { short8 v; u16 u[8]; };
union U4 { u64 ll; u16 u[4]; };

// ---------------- prep: bucket + d_out zero + COALESCED weight pack ----------------
template <int KGS, int NTILES>
__device__ __forceinline__ void pack_tile(const float* __restrict__ W,
                                          u16* __restrict__ dst,
                                          int s, int t2, u16* lds) {
    const int K = KGS * 32;
    const int K4 = K / 4;                  // compile-time -> magic div
    int t = threadIdx.x;
    const float* wbase = W + ((size_t)(s * NTILES + t2) * 16) * K;
    for (int i = t; i < 16 * K4; i += 256) {
        int r = i / K4, c = i % K4;
        float4 v = ((const float4*)(wbase + (size_t)r * K))[c];
        u16* d = lds + r * K + c * 4;
        d[0] = bfr(v.x); d[1] = bfr(v.y); d[2] = bfr(v.z); d[3] = bfr(v.w);
    }
    __syncthreads();
    int w = t >> 6, lane = t & 63;
    int n = lane & 15, ks = lane >> 4;
    for (int kg = w; kg < KGS; kg += 4) {
        short8 v = *reinterpret_cast<const short8*>(lds + n * K + kg * 32 + ks * 8);
        *reinterpret_cast<short8*>(
            dst + (((size_t)(s * NTILES + t2) * KGS + kg) * 64 + lane) * 8) = v;
    }
}

__global__ void prep_kernel(const int* __restrict__ species,
                            int* __restrict__ g_cnt, u16* __restrict__ bucket,
                            const float* __restrict__ W1, const float* __restrict__ W2,
                            const float* __restrict__ W3,
                            u16* __restrict__ w1p, u16* __restrict__ w2p,
                            u16* __restrict__ w3p, float* __restrict__ out) {
    __shared__ u16 lds[16 * 384];
    __shared__ int l_cnt[NSPEC];
    __shared__ int l_base[NSPEC];
    int t = threadIdx.x;
    int bx = blockIdx.x;
    if (bx < BUCKET_BLOCKS) {
        if (bx == 0) {  // zero d_out (1024 floats); mlp runs strictly after us
            float4 z = {0.f, 0.f, 0.f, 0.f};
            ((float4*)out)[t] = z;
        }
        if (t < NSPEC) l_cnt[t] = 0;
        __syncthreads();
        int i = bx * 256 + t;
        int s = species[i];
        int lpos = atomicAdd(&l_cnt[s], 1);
        __syncthreads();
        if (t < NSPEC) l_base[t] = atomicAdd(&g_cnt[t], l_cnt[t]);
        __syncthreads();
        bucket[s * NATOMS + l_base[s] + lpos] = (u16)i;
    } else if (bx < BUCKET_BLOCKS + PACK1_BLOCKS) {
        int pid = bx - BUCKET_BLOCKS;
        pack_tile<12, 16>(W1, w1p, pid / 16, pid % 16, lds);
    } else if (bx < BUCKET_BLOCKS + PACK1_BLOCKS + PACK2_BLOCKS) {
        int pid = bx - (BUCKET_BLOCKS + PACK1_BLOCKS);
        pack_tile<8, 12>(W2, w2p, pid / 12, pid % 12, lds);
    } else {
        int pid = bx - (BUCKET_BLOCKS + PACK1_BLOCKS + PACK2_BLOCKS);
        pack_tile<6, 10>(W3, w3p, pid / 10, pid % 10, lds);
    }
}

// ---------------- MFMA layer: tile-split across the block's 2 waves ----------------
// Wave w computes tiles t = 2*i + w. Weights as MFMA A-operand → D rows =
// neurons: each lane's 4 accs are 4 consecutive neurons of one atom → one
// ds_write_b64 per acc + float4 bias load.
template <int KGS, int NT, int NBUF>
__device__ __forceinline__ void run_layer(const short8* af0, const short8* af1,
                                          const u16* __restrict__ wsp,   // pre-offset
                                          const float* __restrict__ bias, // pre-offset
                                          u16* __restrict__ outbuf, int lane, int w) {
    const int NTL = NT / 2;                 // own tiles per wave
    const int nl = lane & 15, kg4 = lane >> 4;
    // pre-offset to this wave's first tile (tile index w); tiles advance by 2
    const u16* wb = wsp + (size_t)lane * 8 + (size_t)w * KGS * 512;
    short8 b[NBUF][KGS];
#pragma unroll
    for (int p = 0; p < NBUF - 1; ++p)
#pragma unroll
        for (int kg = 0; kg < KGS; ++kg)
            b[p][kg] = *reinterpret_cast<const short8*>(wb + ((size_t)p * 2 * KGS + kg) * 512);
#pragma unroll
    for (int i = 0; i < NTL; ++i) {
        int pre = i + NBUF - 1;
        if (pre < NTL) {
            int slot = pre % NBUF;
#pragma unroll
            for (int kg = 0; kg < KGS; ++kg)
                b[slot][kg] = *reinterpret_cast<const short8*>(wb + ((size_t)pre * 2 * KGS + kg) * 512);
        }
        int cur = i % NBUF;
        floatx4 acc0 = {0.f, 0.f, 0.f, 0.f};
        floatx4 acc1 = {0.f, 0.f, 0.f, 0.f};
#pragma unroll
        for (int kg = 0; kg < KGS; ++kg) {
            acc0 = __builtin_amdgcn_mfma_f32_16x16x32_bf16(b[cur][kg], af0[kg], acc0, 0, 0, 0);
            acc1 = __builtin_amdgcn_mfma_f32_16x16x32_bf16(b[cur][kg], af1[kg], acc1, 0, 0, 0);
        }
        int t = 2 * i + w;                  // global tile -> output col block
        floatx4 bn = *reinterpret_cast<const floatx4*>(bias + t * 16 + kg4 * 4);
        U4 p0, p1;
#pragma unroll
        for (int r = 0; r < 4; ++r) {
            p0.u[r] = bfr(celu01(acc0[r] + bn[r]));
            p1.u[r] = bfr(celu01(acc1[r] + bn[r]));
        }
        *reinterpret_cast<u64*>(outbuf + (size_t)nl * BUFST + t * 16 + kg4 * 4) = p0.ll;
        *reinterpret_cast<u64*>(outbuf + (size_t)(16 + nl) * BUFST + t * 16 + kg4 * 4) = p1.ll;
    }
}

template <int KGS>
__device__ __forceinline__ void load_a_lds(const u16* __restrict__ buf,
                                           short8* af0, short8* af1, int lane) {
    int nl = lane & 15, kg4 = lane >> 4;
#pragma unroll
    for (int kg = 0; kg < KGS; ++kg) {
        af0[kg] = *reinterpret_cast<const short8*>(buf + (size_t)nl * BUFST + kg * 32 + kg4 * 8);
        af1[kg] = *reinterpret_cast<const short8*>(buf + (size_t)(16 + nl) * BUFST + kg * 32 + kg4 * 8);
    }
}

// Compact 1D grid: block bx maps to (s, chunk) via in-kernel prefix scan of
// g_cnt. Block = 32 atoms, 2 waves tile-split, single in-place LDS buffer.
// __launch_bounds__(128, 2): R3's (128,3) made the compiler split the unified
// gfx950 reg file to 84 VGPR (+~84 AGPR) < the ~200-reg working set -> scratch
// spills (WRITE_SIZE 113 MB/dispatch, 2.3x slowdown). (128,2) restores the
// R0-proven 128V+128A regime: zero scratch, VGPR caps residency at 4 blk/CU.
__global__ __launch_bounds__(128, 2) void mlp_kernel(
    const float* __restrict__ aev,
    const u16* __restrict__ w1p, const u16* __restrict__ w2p, const u16* __restrict__ w3p,
    const float* __restrict__ b1, const float* __restrict__ b2, const float* __restrict__ b3,
    const float* __restrict__ W4, const float* __restrict__ b4,
    const int* __restrict__ g_cnt, const u16* __restrict__ bucket,
    float* __restrict__ out) {
    int bx = blockIdx.x;
    int s = -1, chunk = 0;
    {
        int acc = 0;
#pragma unroll
        for (int q = 0; q < NSPEC; ++q) {
            int nb = (g_cnt[q] + 31) >> 5;          // 32 atoms per block
            if (s < 0 && bx < acc + nb) { s = q; chunk = bx - acc; }
            acc += nb;
        }
        if (s < 0) return;                          // bx beyond total work
    }
    int cnt = g_cnt[s];
    int w = threadIdx.x >> 6, lane = threadIdx.x & 63;
    int base = chunk * 32;               // the block's 32 atoms (both waves)

    // Single 32-row activation buffer; tile-split writes are disjoint;
    // write->read and read->overwrite (WAR) barriers separate the phases.
    __shared__ __align__(16) u16 buf[32 * BUFST];  // 16896 B/block

    int nl = lane & 15, kg4 = lane >> 4;

    // ---- layer 1: 384 -> 256. A from global fp32 aev (plain loads: aev is
    // L3-resident across iterations — NT loads forced 105 MB/iter HBM
    // re-streaming in R2; reverted). Both waves load the same A. ----
    short8 af0[12], af1[12];
    {
        int i0 = base + nl;       if (i0 >= cnt) i0 = cnt - 1;
        int i1 = base + 16 + nl;  if (i1 >= cnt) i1 = cnt - 1;
        int a0 = (int)bucket[s * NATOMS + i0];
        int a1 = (int)bucket[s * NATOMS + i1];
        const float* ar0 = aev + (size_t)a0 * FDIM;
        const float* ar1 = aev + (size_t)a1 * FDIM;
#pragma unroll
        for (int kg = 0; kg < 12; ++kg) {
            const float4* p0 = (const float4*)(ar0 + kg * 32 + kg4 * 8);
            const float4* p1 = (const float4*)(ar1 + kg * 32 + kg4 * 8);
            float4 a = p0[0], b = p0[1];
            float4 c = p1[0], d = p1[1];
            U8 x, y;
            x.u[0] = bfr(a.x); x.u[1] = bfr(a.y); x.u[2] = bfr(a.z); x.u[3] = bfr(a.w);
            x.u[4] = bfr(b.x); x.u[5] = bfr(b.y); x.u[6] = bfr(b.z); x.u[7] = bfr(b.w);
            y.u[0] = bfr(c.x); y.u[1] = bfr(c.y); y.u[2] = bfr(c.z); y.u[3] = bfr(c.w);
            y.u[4] = bfr(d.x); y.u[5] = bfr(d.y); y.u[6] = bfr(d.z); y.u[7] = bfr(d.w);
            af0[kg] = x.v;
            af1[kg] = y.v;
        }
    }
    run_layer<12, 16, 2>(af0, af1, w1p + (size_t)s * W1_ELEMS_PER_S, b1 + s * 256, buf, lane, w);
    __syncthreads();                       // L1 writes -> visible

    // ---- layer 2: 256 -> 192 ----
    short8 c0[8], c1[8];
    load_a_lds<8>(buf, c0, c1, lane);
    __syncthreads();                       // WAR: both waves' reads done before overwrite
    run_layer<8, 12, 3>(c0, c1, w2p + (size_t)s * W2_ELEMS_PER_S, b2 + s * 192, buf, lane, w);
    __syncthreads();                       // L2 writes -> visible

    // ---- layer 3: 192 -> 160 ----
    short8 d0[6], d1[6];
    load_a_lds<6>(buf, d0, d1, lane);
    __syncthreads();                       // WAR
    run_layer<6, 10, 3>(d0, d1, w3p + (size_t)s * W3_ELEMS_PER_S, b3 + s * 160, buf, lane, w);
    __syncthreads();                       // L3 writes -> visible

    // ---- layer 4: 160 -> 1 (fp32 VALU), 2 lanes/atom; wave w does atoms
    // [w*16, w*16+16) with lanes 0..31, + molecule scatter-add ----
    {
        int m = lane >> 1, q = lane & 1;
        if (m < 16) {
            int ai = w * 16 + m;
            const u16* h = buf + (size_t)ai * BUFST + q * 80;
            const float* w4s = W4 + s * 160 + q * 80;
            float p = 0.f;
#pragma unroll
            for (int c = 0; c < 10; ++c) {
                short8 hv = *reinterpret_cast<const short8*>(h + c * 8);
                const float4* wp4 = (const float4*)(w4s + c * 8);
                float4 wa = wp4[0], wb = wp4[1];
                p += bf2f(hv[0]) * wa.x + bf2f(hv[1]) * wa.y + bf2f(hv[2]) * wa.z + bf2f(hv[3]) * wa.w;
                p += bf2f(hv[4]) * wb.x + bf2f(hv[5]) * wb.y + bf2f(hv[6]) * wb.z + bf2f(hv[7]) * wb.w;
            }
            p += __shfl_down(p, 1, 2);
            int idx = base + ai;
            if (q == 0 && idx < cnt) {
                int atom = (int)bucket[s * NATOMS + idx];
                atomicAdd(&out[atom / APM], p + b4[s]);
            }
        }
    }
}

extern "C" void kernel_launch(void* const* d_in, const int* in_sizes, int n_in,
                              void* d_out, int out_size, void* d_ws, size_t ws_size,
                              hipStream_t stream) {
    const int* species = (const int*)d_in[0];
    const float* aev = (const float*)d_in[1];
    const float* W1 = (const float*)d_in[2];
    const float* b1 = (const float*)d_in[3];
    const float* W2 = (const float*)d_in[4];
    const float* b2 = (const float*)d_in[5];
    const float* W3 = (const float*)d_in[6];
    const float* b3 = (const float*)d_in[7];
    const float* W4 = (const float*)d_in[8];
    const float* b4 = (const float*)d_in[9];
    float* out = (float*)d_out;

    unsigned char* wsb = (unsigned char*)d_ws;
    int* g_cnt = (int*)wsb;
    u16* w1p = (u16*)(wsb + WS_W1_OFF);
    u16* w2p = (u16*)(wsb + WS_W2_OFF);
    u16* w3p = (u16*)(wsb + WS_W3_OFF);
    u16* bucket = (u16*)(wsb + WS_BKT_OFF);

    hipMemsetAsync(g_cnt, 0, 8 * sizeof(int), stream);

    prep_kernel<<<PREP_BLOCKS, 256, 0, stream>>>(
        species, g_cnt, bucket, W1, W2, W3, w1p, w2p, w3p, out);

    mlp_kernel<<<MLP_BLOCKS, 128, 0, stream>>>(
        aev, w1p, w2p, w3p, b1, b2, b3, W4, b4, g_cnt, bucket, out);
}

// Round 5
// 181.265 us; speedup vs baseline: 1.3346x; 1.0483x over previous
//
#include <hip/hip_runtime.h>
#include <math.h>

#define NSPEC 7
#define NMOL 1024
#define APM 48
#define NATOMS (NMOL * APM)   // 49152
#define FDIM 384

typedef unsigned short u16;
typedef unsigned int u32;
typedef unsigned long long u64;
typedef __attribute__((ext_vector_type(8))) short short8;
typedef __attribute__((ext_vector_type(4))) float floatx4;

// Packed-weight geometry: [s][ntile][kg][lane(64)][8] bf16, frag = 16B/lane.
#define W1_ELEMS_PER_S (16 * 12 * 64 * 8)   // 98304
#define W2_ELEMS_PER_S (12 * 8 * 64 * 8)    // 49152
#define W3_ELEMS_PER_S (10 * 6 * 64 * 8)    // 30720

#define BUCKET_BLOCKS (NATOMS / 256)        // 192
#define PACK1_BLOCKS (NSPEC * 16)           // 112 (one block per (s, ntile))
#define PACK2_BLOCKS (NSPEC * 12)           // 84
#define PACK3_BLOCKS (NSPEC * 10)           // 70
#define PREP_BLOCKS (BUCKET_BLOCKS + PACK1_BLOCKS + PACK2_BLOCKS + PACK3_BLOCKS)

// R5: 16 atoms per wave, ONE wave per 64-thread block, fully wave-private
// (no barriers anywhere — R1-R4 showed barrier-coupled parallelism loses).
// Σ_s ceil(cnt_s/16) ≤ 3072 + 6 = 3078 blocks ≈ 12 waves/CU.
#define MLP_BLOCKS 3078

// ws layout (bytes): g_cnt[8] @0, w1p @32, w2p, w3p, bucket u16[7*NATOMS]. ~3.2 MB.
#define WS_W1_OFF 32
#define WS_W2_OFF (WS_W1_OFF + 1376256)
#define WS_W3_OFF (WS_W2_OFF + 688128)
#define WS_BKT_OFF (WS_W3_OFF + 430080)

#define BUFST 264   // LDS activation row stride in u16 (132 dw ≡ 4 mod 32: 2-way/free banks)

__device__ __forceinline__ float celu01(float x) {
    // celu(x,0.1) = x>0 ? x : 0.1*(exp(10x)-1); __expf = native v_exp (~6 VALU).
    float e = fmaf(0.1f, __expf(x * 10.0f), -0.1f);
    return x > 0.0f ? x : e;
}

__device__ __forceinline__ u16 bfr(float f) {  // fp32 -> bf16 RNE
    u32 u = __float_as_uint(f);
    u += 0x7fffu + ((u >> 16) & 1u);
    return (u16)(u >> 16);
}

__device__ __forceinline__ float bf2f(short s) {
    return __uint_as_float(((u32)(u16)s) << 16);
}

union U8 { short8 v; u16 u[8]; };
union U4 { u64 ll; u16 u[4]; };

// ---------------- prep: bucket + d_out zero + COALESCED weight pack ----------------
template <int KGS, int NTILES>
__device__ __forceinline__ void pack_tile(const float* __restrict__ W,
                                          u16* __restrict__ dst,
                                          int s, int t2, u16* lds) {
    const int K = KGS * 32;
    const int K4 = K / 4;                  // compile-time -> magic div
    int t = threadIdx.x;
    const float* wbase = W + ((size_t)(s * NTILES + t2) * 16) * K;
    for (int i = t; i < 16 * K4; i += 256) {
        int r = i / K4, c = i % K4;
        float4 v = ((const float4*)(wbase + (size_t)r * K))[c];
        u16* d = lds + r * K + c * 4;
        d[0] = bfr(v.x); d[1] = bfr(v.y); d[2] = bfr(v.z); d[3] = bfr(v.w);
    }
    __syncthreads();
    int w = t >> 6, lane = t & 63;
    int n = lane & 15, ks = lane >> 4;
    for (int kg = w; kg < KGS; kg += 4) {
        short8 v = *reinterpret_cast<const short8*>(lds + n * K + kg * 32 + ks * 8);
        *reinterpret_cast<short8*>(
            dst + (((size_t)(s * NTILES + t2) * KGS + kg) * 64 + lane) * 8) = v;
    }
}

__global__ void prep_kernel(const int* __restrict__ species,
                            int* __restrict__ g_cnt, u16* __restrict__ bucket,
                            const float* __restrict__ W1, const float* __restrict__ W2,
                            const float* __restrict__ W3,
                            u16* __restrict__ w1p, u16* __restrict__ w2p,
                            u16* __restrict__ w3p, float* __restrict__ out) {
    __shared__ u16 lds[16 * 384];
    __shared__ int l_cnt[NSPEC];
    __shared__ int l_base[NSPEC];
    int t = threadIdx.x;
    int bx = blockIdx.x;
    if (bx < BUCKET_BLOCKS) {
        if (bx == 0) {  // zero d_out (1024 floats); mlp runs strictly after us
            float4 z = {0.f, 0.f, 0.f, 0.f};
            ((float4*)out)[t] = z;
        }
        if (t < NSPEC) l_cnt[t] = 0;
        __syncthreads();
        int i = bx * 256 + t;
        int s = species[i];
        int lpos = atomicAdd(&l_cnt[s], 1);
        __syncthreads();
        if (t < NSPEC) l_base[t] = atomicAdd(&g_cnt[t], l_cnt[t]);
        __syncthreads();
        bucket[s * NATOMS + l_base[s] + lpos] = (u16)i;
    } else if (bx < BUCKET_BLOCKS + PACK1_BLOCKS) {
        int pid = bx - BUCKET_BLOCKS;
        pack_tile<12, 16>(W1, w1p, pid / 16, pid % 16, lds);
    } else if (bx < BUCKET_BLOCKS + PACK1_BLOCKS + PACK2_BLOCKS) {
        int pid = bx - (BUCKET_BLOCKS + PACK1_BLOCKS);
        pack_tile<8, 12>(W2, w2p, pid / 12, pid % 12, lds);
    } else {
        int pid = bx - (BUCKET_BLOCKS + PACK1_BLOCKS + PACK2_BLOCKS);
        pack_tile<6, 10>(W3, w3p, pid / 10, pid % 10, lds);
    }
}

// ---------------- MFMA layer: 16 atoms/wave, half-tile-pipelined weights ----------------
// Weight stream is consumed in half-tiles (HALF = KGS/2 k-groups), triple-
// buffered: 2 half-tiles (= HALF*2 loads) always in flight, at ~60% of the
// register cost of full-tile double-buffering. Weights are the MFMA A-operand
// (D row = neuron, D col = atom): each lane's 4 accs are 4 consecutive
// neurons of one atom -> one ds_write_b64 + float4 bias load per tile.
template <int KGS, int NT>
__device__ __forceinline__ void run_layer16(const short8* af,
                                            const u16* __restrict__ wsp,   // pre-offset
                                            const float* __restrict__ bias, // pre-offset
                                            u16* __restrict__ outbuf, int lane) {
    const int HALF = KGS / 2;
    const int NH = NT * 2;                  // half-steps
    const int nl = lane & 15, kg4 = lane >> 4;
    const u16* wb = wsp + (size_t)lane * 8;
    // half-step p covers tile p>>1, k-groups (p&1)*HALF..+HALF-1; flat frag
    // offset (p*HALF + k)*512 u16 (since tile stride = KGS*512 = 2*HALF*512).
    short8 b[3][HALF];
#pragma unroll
    for (int p = 0; p < 2; ++p)
#pragma unroll
        for (int k = 0; k < HALF; ++k)
            b[p][k] = *reinterpret_cast<const short8*>(wb + ((size_t)p * HALF + k) * 512);
    floatx4 acc = {0.f, 0.f, 0.f, 0.f};
#pragma unroll
    for (int h = 0; h < NH; ++h) {
        int pre = h + 2;
        if (pre < NH) {
#pragma unroll
            for (int k = 0; k < HALF; ++k)
                b[pre % 3][k] = *reinterpret_cast<const short8*>(wb + ((size_t)pre * HALF + k) * 512);
        }
#pragma unroll
        for (int k = 0; k < HALF; ++k)
            acc = __builtin_amdgcn_mfma_f32_16x16x32_bf16(b[h % 3][k], af[(h & 1) * HALF + k], acc, 0, 0, 0);
        if (h & 1) {                        // tile complete -> bias+celu+store
            int t = h >> 1;
            floatx4 bn = *reinterpret_cast<const floatx4*>(bias + t * 16 + kg4 * 4);
            U4 pk;
#pragma unroll
            for (int r = 0; r < 4; ++r)
                pk.u[r] = bfr(celu01(acc[r] + bn[r]));
            *reinterpret_cast<u64*>(outbuf + (size_t)nl * BUFST + t * 16 + kg4 * 4) = pk.ll;
            acc = (floatx4){0.f, 0.f, 0.f, 0.f};
        }
    }
}

template <int KGS>
__device__ __forceinline__ void load_a16(const u16* __restrict__ buf,
                                         short8* af, int lane) {
    int nl = lane & 15, kg4 = lane >> 4;
#pragma unroll
    for (int kg = 0; kg < KGS; ++kg)
        af[kg] = *reinterpret_cast<const short8*>(buf + (size_t)nl * BUFST + kg * 32 + kg4 * 8);
}

// Compact 1D grid: block bx -> (s, chunk) via in-kernel prefix scan of g_cnt.
// Block = 1 wave = 16 atoms, fully private: no __syncthreads anywhere.
// __launch_bounds__(64, 3): 170-reg cap fits the ~155-reg peak (L1: af 48 +
// b[3][6] 72 + acc/addr) -> 3 waves/SIMD resident, grid avg 12 waves/CU.
__global__ __launch_bounds__(64, 3) void mlp_kernel(
    const float* __restrict__ aev,
    const u16* __restrict__ w1p, const u16* __restrict__ w2p, const u16* __restrict__ w3p,
    const float* __restrict__ b1, const float* __restrict__ b2, const float* __restrict__ b3,
    const float* __restrict__ W4, const float* __restrict__ b4,
    const int* __restrict__ g_cnt, const u16* __restrict__ bucket,
    float* __restrict__ out) {
    int bx = blockIdx.x;
    int s = -1, chunk = 0;
    {
        int acc = 0;
#pragma unroll
        for (int q = 0; q < NSPEC; ++q) {
            int nb = (g_cnt[q] + 15) >> 4;          // 16 atoms per block
            if (s < 0 && bx < acc + nb) { s = q; chunk = bx - acc; }
            acc += nb;
        }
        if (s < 0) return;                          // bx beyond total work
    }
    int cnt = g_cnt[s];
    int lane = threadIdx.x & 63;
    int base = chunk * 16;               // this wave's 16 atoms

    // Wave-private LDS activation buffer, reused in place across layers
    // (A is consumed into registers before outputs are written).
    __shared__ __align__(16) u16 buf[16 * BUFST];  // 8448 B/block

    int nl = lane & 15, kg4 = lane >> 4;

    // ---- layer 1: 384 -> 256. A from global fp32 aev (plain loads: L3-
    // resident across iterations; NT loads regressed 2x in R2), converted
    // in-register. One atom row per nl. ----
    short8 af[12];
    {
        int i0 = base + nl;  if (i0 >= cnt) i0 = cnt - 1;
        int a0 = (int)bucket[s * NATOMS + i0];
        const float* ar0 = aev + (size_t)a0 * FDIM;
#pragma unroll
        for (int kg = 0; kg < 12; ++kg) {
            const float4* p0 = (const float4*)(ar0 + kg * 32 + kg4 * 8);
            float4 a = p0[0], b = p0[1];
            U8 x;
            x.u[0] = bfr(a.x); x.u[1] = bfr(a.y); x.u[2] = bfr(a.z); x.u[3] = bfr(a.w);
            x.u[4] = bfr(b.x); x.u[5] = bfr(b.y); x.u[6] = bfr(b.z); x.u[7] = bfr(b.w);
            af[kg] = x.v;
        }
    }
    run_layer16<12, 16>(af, w1p + (size_t)s * W1_ELEMS_PER_S, b1 + s * 256, buf, lane);

    // ---- layer 2: 256 -> 192 ----
    short8 c[8];
    load_a16<8>(buf, c, lane);
    run_layer16<8, 12>(c, w2p + (size_t)s * W2_ELEMS_PER_S, b2 + s * 192, buf, lane);

    // ---- layer 3: 192 -> 160 ----
    short8 d[6];
    load_a16<6>(buf, d, lane);
    run_layer16<6, 10>(d, w3p + (size_t)s * W3_ELEMS_PER_S, b3 + s * 160, buf, lane);

    // ---- layer 4: 160 -> 1 (fp32 VALU), 4 lanes/atom (40 feats each),
    // shfl-reduce width 4, + molecule scatter-add ----
    {
        int m = lane >> 2, q = lane & 3;
        const u16* h = buf + (size_t)m * BUFST + q * 40;
        const float* w4s = W4 + s * 160 + q * 40;
        float p = 0.f;
#pragma unroll
        for (int cc = 0; cc < 5; ++cc) {
            short8 hv = *reinterpret_cast<const short8*>(h + cc * 8);
            const float4* wp4 = (const float4*)(w4s + cc * 8);
            float4 wa = wp4[0], wb = wp4[1];
            p += bf2f(hv[0]) * wa.x + bf2f(hv[1]) * wa.y + bf2f(hv[2]) * wa.z + bf2f(hv[3]) * wa.w;
            p += bf2f(hv[4]) * wb.x + bf2f(hv[5]) * wb.y + bf2f(hv[6]) * wb.z + bf2f(hv[7]) * wb.w;
        }
        p += __shfl_down(p, 2, 4);
        p += __shfl_down(p, 1, 4);
        int idx = base + m;
        if (q == 0 && idx < cnt) {
            int atom = (int)bucket[s * NATOMS + idx];
            atomicAdd(&out[atom / APM], p + b4[s]);
        }
    }
}

extern "C" void kernel_launch(void* const* d_in, const int* in_sizes, int n_in,
                              void* d_out, int out_size, void* d_ws, size_t ws_size,
                              hipStream_t stream) {
    const int* species = (const int*)d_in[0];
    const float* aev = (const float*)d_in[1];
    const float* W1 = (const float*)d_in[2];
    const float* b1 = (const float*)d_in[3];
    const float* W2 = (const float*)d_in[4];
    const float* b2 = (const float*)d_in[5];
    const float* W3 = (const float*)d_in[6];
    const float* b3 = (const float*)d_in[7];
    const float* W4 = (const float*)d_in[8];
    const float* b4 = (const float*)d_in[9];
    float* out = (float*)d_out;

    unsigned char* wsb = (unsigned char*)d_ws;
    int* g_cnt = (int*)wsb;
    u16* w1p = (u16*)(wsb + WS_W1_OFF);
    u16* w2p = (u16*)(wsb + WS_W2_OFF);
    u16* w3p = (u16*)(wsb + WS_W3_OFF);
    u16* bucket = (u16*)(wsb + WS_BKT_OFF);

    hipMemsetAsync(g_cnt, 0, 8 * sizeof(int), stream);

    prep_kernel<<<PREP_BLOCKS, 256, 0, stream>>>(
        species, g_cnt, bucket, W1, W2, W3, w1p, w2p, w3p, out);

    mlp_kernel<<<MLP_BLOCKS, 64, 0, stream>>>(
        aev, w1p, w2p, w3p, b1, b2, b3, W4, b4, g_cnt, bucket, out);
}

// Round 6
// 180.246 us; speedup vs baseline: 1.3421x; 1.0056x over previous
//
#include <hip/hip_runtime.h>
#include <math.h>

#define NSPEC 7
#define NMOL 1024
#define APM 48
#define NATOMS (NMOL * APM)   // 49152
#define FDIM 384

typedef unsigned short u16;
typedef unsigned int u32;
typedef unsigned long long u64;
typedef __attribute__((ext_vector_type(8))) short short8;
typedef __attribute__((ext_vector_type(4))) float floatx4;

// Packed-weight geometry: [s][ntile][kg][lane(64)][8] bf16, frag = 16B/lane.
#define W1_ELEMS_PER_S (16 * 12 * 64 * 8)   // 98304
#define W2_ELEMS_PER_S (12 * 8 * 64 * 8)    // 49152
#define W3_ELEMS_PER_S (10 * 6 * 64 * 8)    // 30720

#define BUCKET_BLOCKS (NATOMS / 256)        // 192
#define PACK1_BLOCKS (NSPEC * 16)           // 112 (one block per (s, ntile))
#define PACK2_BLOCKS (NSPEC * 12)           // 84
#define PACK3_BLOCKS (NSPEC * 10)           // 70
#define PREP_BLOCKS (BUCKET_BLOCKS + PACK1_BLOCKS + PACK2_BLOCKS + PACK3_BLOCKS)

// 16 atoms per wave, ONE wave per 64-thread block, fully wave-private
// (no barriers anywhere). Σ_s ceil(cnt_s/16) ≤ 3072 + 6 = 3078 blocks.
#define MLP_BLOCKS 3078

// ws layout (bytes): g_cnt[8] @0, w1p @32, w2p, w3p, bucket u16[7*NATOMS]. ~3.2 MB.
#define WS_W1_OFF 32
#define WS_W2_OFF (WS_W1_OFF + 1376256)
#define WS_W3_OFF (WS_W2_OFF + 688128)
#define WS_BKT_OFF (WS_W3_OFF + 430080)

#define BUFST 264   // LDS activation row stride in u16 (132 dw ≡ 4 mod 32: 2-way/free banks)

__device__ __forceinline__ float celu01(float x) {
    // celu(x,0.1) = x>0 ? x : 0.1*(exp(10x)-1); __expf = native v_exp (~6 VALU).
    float e = fmaf(0.1f, __expf(x * 10.0f), -0.1f);
    return x > 0.0f ? x : e;
}

__device__ __forceinline__ u16 bfr(float f) {  // fp32 -> bf16 RNE
    u32 u = __float_as_uint(f);
    u += 0x7fffu + ((u >> 16) & 1u);
    return (u16)(u >> 16);
}

__device__ __forceinline__ float bf2f(short s) {
    return __uint_as_float(((u32)(u16)s) << 16);
}

union U8 { short8 v; u16 u[8]; };
union U4 { u64 ll; u16 u[4]; };

// ---------------- prep: bucket + d_out zero + COALESCED weight pack ----------------
template <int KGS, int NTILES>
__device__ __forceinline__ void pack_tile(const float* __restrict__ W,
                                          u16* __restrict__ dst,
                                          int s, int t2, u16* lds) {
    const int K = KGS * 32;
    const int K4 = K / 4;                  // compile-time -> magic div
    int t = threadIdx.x;
    const float* wbase = W + ((size_t)(s * NTILES + t2) * 16) * K;
    for (int i = t; i < 16 * K4; i += 256) {
        int r = i / K4, c = i % K4;
        float4 v = ((const float4*)(wbase + (size_t)r * K))[c];
        u16* d = lds + r * K + c * 4;
        d[0] = bfr(v.x); d[1] = bfr(v.y); d[2] = bfr(v.z); d[3] = bfr(v.w);
    }
    __syncthreads();
    int w = t >> 6, lane = t & 63;
    int n = lane & 15, ks = lane >> 4;
    for (int kg = w; kg < KGS; kg += 4) {
        short8 v = *reinterpret_cast<const short8*>(lds + n * K + kg * 32 + ks * 8);
        *reinterpret_cast<short8*>(
            dst + (((size_t)(s * NTILES + t2) * KGS + kg) * 64 + lane) * 8) = v;
    }
}

__global__ void prep_kernel(const int* __restrict__ species,
                            int* __restrict__ g_cnt, u16* __restrict__ bucket,
                            const float* __restrict__ W1, const float* __restrict__ W2,
                            const float* __restrict__ W3,
                            u16* __restrict__ w1p, u16* __restrict__ w2p,
                            u16* __restrict__ w3p, float* __restrict__ out) {
    __shared__ u16 lds[16 * 384];
    __shared__ int l_cnt[NSPEC];
    __shared__ int l_base[NSPEC];
    int t = threadIdx.x;
    int bx = blockIdx.x;
    if (bx < BUCKET_BLOCKS) {
        if (bx == 0) {  // zero d_out (1024 floats); mlp runs strictly after us
            float4 z = {0.f, 0.f, 0.f, 0.f};
            ((float4*)out)[t] = z;
        }
        if (t < NSPEC) l_cnt[t] = 0;
        __syncthreads();
        int i = bx * 256 + t;
        int s = species[i];
        int lpos = atomicAdd(&l_cnt[s], 1);
        __syncthreads();
        if (t < NSPEC) l_base[t] = atomicAdd(&g_cnt[t], l_cnt[t]);
        __syncthreads();
        bucket[s * NATOMS + l_base[s] + lpos] = (u16)i;
    } else if (bx < BUCKET_BLOCKS + PACK1_BLOCKS) {
        int pid = bx - BUCKET_BLOCKS;
        pack_tile<12, 16>(W1, w1p, pid / 16, pid % 16, lds);
    } else if (bx < BUCKET_BLOCKS + PACK1_BLOCKS + PACK2_BLOCKS) {
        int pid = bx - (BUCKET_BLOCKS + PACK1_BLOCKS);
        pack_tile<8, 12>(W2, w2p, pid / 12, pid % 12, lds);
    } else {
        int pid = bx - (BUCKET_BLOCKS + PACK1_BLOCKS + PACK2_BLOCKS);
        pack_tile<6, 10>(W3, w3p, pid / 10, pid % 10, lds);
    }
}

// ---------------- MFMA layer: 16 atoms/wave, DEPTH half-tile-pipelined weights ----------------
// Weight stream consumed in half-tiles (HALF = KGS/2 k-groups), DEPTH-deep
// rotation: DEPTH-1 half-tiles always in flight ahead of consumption.
// Weights are the MFMA A-operand (D row = neuron, D col = atom): each lane's
// 4 accs are 4 consecutive neurons of one atom -> one ds_write_b64 + float4
// bias load per tile. All buffer indices compile-time (rule: no dyn-idx regs).
template <int KGS, int NT, int DEPTH>
__device__ __forceinline__ void run_layer16(const short8* af,
                                            const u16* __restrict__ wsp,   // pre-offset
                                            const float* __restrict__ bias, // pre-offset
                                            u16* __restrict__ outbuf, int lane) {
    const int HALF = KGS / 2;
    const int NH = NT * 2;                  // half-steps
    const int nl = lane & 15, kg4 = lane >> 4;
    const u16* wb = wsp + (size_t)lane * 8;
    // half-step p covers tile p>>1, k-groups (p&1)*HALF..+HALF-1; flat frag
    // offset (p*HALF + k)*512 u16 (tile stride = KGS*512 = 2*HALF*512).
    short8 b[DEPTH][HALF];
#pragma unroll
    for (int p = 0; p < DEPTH - 1; ++p)
#pragma unroll
        for (int k = 0; k < HALF; ++k)
            b[p][k] = *reinterpret_cast<const short8*>(wb + ((size_t)p * HALF + k) * 512);
    floatx4 acc = {0.f, 0.f, 0.f, 0.f};
#pragma unroll
    for (int h = 0; h < NH; ++h) {
        int pre = h + DEPTH - 1;
        if (pre < NH) {
#pragma unroll
            for (int k = 0; k < HALF; ++k)
                b[pre % DEPTH][k] = *reinterpret_cast<const short8*>(wb + ((size_t)pre * HALF + k) * 512);
        }
#pragma unroll
        for (int k = 0; k < HALF; ++k)
            acc = __builtin_amdgcn_mfma_f32_16x16x32_bf16(b[h % DEPTH][k], af[(h & 1) * HALF + k], acc, 0, 0, 0);
        if (h & 1) {                        // tile complete -> bias+celu+store
            int t = h >> 1;
            floatx4 bn = *reinterpret_cast<const floatx4*>(bias + t * 16 + kg4 * 4);
            U4 pk;
#pragma unroll
            for (int r = 0; r < 4; ++r)
                pk.u[r] = bfr(celu01(acc[r] + bn[r]));
            *reinterpret_cast<u64*>(outbuf + (size_t)nl * BUFST + t * 16 + kg4 * 4) = pk.ll;
            acc = (floatx4){0.f, 0.f, 0.f, 0.f};
        }
    }
}

template <int KGS>
__device__ __forceinline__ void load_a16(const u16* __restrict__ buf,
                                         short8* af, int lane) {
    int nl = lane & 15, kg4 = lane >> 4;
#pragma unroll
    for (int kg = 0; kg < KGS; ++kg)
        af[kg] = *reinterpret_cast<const short8*>(buf + (size_t)nl * BUFST + kg * 32 + kg4 * 8);
}

// Compact 1D grid: block bx -> (s, chunk) via in-kernel prefix scan of g_cnt.
// Block = 1 wave = 16 atoms, fully private: no __syncthreads anywhere.
// __launch_bounds__(64, 2): 256-reg unified cap. Every min_waves=3 build
// (R3, R5) split the file to ~84 arch VGPR < the ~150-reg working set ->
// scratch spills (13 MB WRITE, wave lifetime 48 µs). 256-reg cap fits the
// depth-4 working set (af 48 + b[4][6] 96 + misc ~25) spill-free; the
// allocator splits unevenly by need (m97: 164 V + 64 A).
__global__ __launch_bounds__(64, 2) void mlp_kernel(
    const float* __restrict__ aev,
    const u16* __restrict__ w1p, const u16* __restrict__ w2p, const u16* __restrict__ w3p,
    const float* __restrict__ b1, const float* __restrict__ b2, const float* __restrict__ b3,
    const float* __restrict__ W4, const float* __restrict__ b4,
    const int* __restrict__ g_cnt, const u16* __restrict__ bucket,
    float* __restrict__ out) {
    int bx = blockIdx.x;
    int s = -1, chunk = 0;
    {
        int acc = 0;
#pragma unroll
        for (int q = 0; q < NSPEC; ++q) {
            int nb = (g_cnt[q] + 15) >> 4;          // 16 atoms per block
            if (s < 0 && bx < acc + nb) { s = q; chunk = bx - acc; }
            acc += nb;
        }
        if (s < 0) return;                          // bx beyond total work
    }
    int cnt = g_cnt[s];
    int lane = threadIdx.x & 63;
    int base = chunk * 16;               // this wave's 16 atoms

    // Wave-private LDS activation buffer, reused in place across layers
    // (A is consumed into registers before outputs are written).
    __shared__ __align__(16) u16 buf[16 * BUFST];  // 8448 B/block

    int nl = lane & 15, kg4 = lane >> 4;

    // ---- layer 1: 384 -> 256. A from global fp32 aev (plain loads: L3-
    // resident across iterations; NT loads regressed 2x in R2), converted
    // in-register. One atom row per nl. ----
    short8 af[12];
    {
        int i0 = base + nl;  if (i0 >= cnt) i0 = cnt - 1;
        int a0 = (int)bucket[s * NATOMS + i0];
        const float* ar0 = aev + (size_t)a0 * FDIM;
#pragma unroll
        for (int kg = 0; kg < 12; ++kg) {
            const float4* p0 = (const float4*)(ar0 + kg * 32 + kg4 * 8);
            float4 a = p0[0], b = p0[1];
            U8 x;
            x.u[0] = bfr(a.x); x.u[1] = bfr(a.y); x.u[2] = bfr(a.z); x.u[3] = bfr(a.w);
            x.u[4] = bfr(b.x); x.u[5] = bfr(b.y); x.u[6] = bfr(b.z); x.u[7] = bfr(b.w);
            af[kg] = x.v;
        }
    }
    run_layer16<12, 16, 4>(af, w1p + (size_t)s * W1_ELEMS_PER_S, b1 + s * 256, buf, lane);

    // ---- layer 2: 256 -> 192 ----
    short8 c[8];
    load_a16<8>(buf, c, lane);
    run_layer16<8, 12, 4>(c, w2p + (size_t)s * W2_ELEMS_PER_S, b2 + s * 192, buf, lane);

    // ---- layer 3: 192 -> 160 ----
    short8 d[6];
    load_a16<6>(buf, d, lane);
    run_layer16<6, 10, 4>(d, w3p + (size_t)s * W3_ELEMS_PER_S, b3 + s * 160, buf, lane);

    // ---- layer 4: 160 -> 1 (fp32 VALU), 4 lanes/atom (40 feats each),
    // shfl-reduce width 4, + molecule scatter-add ----
    {
        int m = lane >> 2, q = lane & 3;
        const u16* h = buf + (size_t)m * BUFST + q * 40;
        const float* w4s = W4 + s * 160 + q * 40;
        float p = 0.f;
#pragma unroll
        for (int cc = 0; cc < 5; ++cc) {
            short8 hv = *reinterpret_cast<const short8*>(h + cc * 8);
            const float4* wp4 = (const float4*)(w4s + cc * 8);
            float4 wa = wp4[0], wb = wp4[1];
            p += bf2f(hv[0]) * wa.x + bf2f(hv[1]) * wa.y + bf2f(hv[2]) * wa.z + bf2f(hv[3]) * wa.w;
            p += bf2f(hv[4]) * wb.x + bf2f(hv[5]) * wb.y + bf2f(hv[6]) * wb.z + bf2f(hv[7]) * wb.w;
        }
        p += __shfl_down(p, 2, 4);
        p += __shfl_down(p, 1, 4);
        int idx = base + m;
        if (q == 0 && idx < cnt) {
            int atom = (int)bucket[s * NATOMS + idx];
            atomicAdd(&out[atom / APM], p + b4[s]);
        }
    }
}

extern "C" void kernel_launch(void* const* d_in, const int* in_sizes, int n_in,
                              void* d_out, int out_size, void* d_ws, size_t ws_size,
                              hipStream_t stream) {
    const int* species = (const int*)d_in[0];
    const float* aev = (const float*)d_in[1];
    const float* W1 = (const float*)d_in[2];
    const float* b1 = (const float*)d_in[3];
    const float* W2 = (const float*)d_in[4];
    const float* b2 = (const float*)d_in[5];
    const float* W3 = (const float*)d_in[6];
    const float* b3 = (const float*)d_in[7];
    const float* W4 = (const float*)d_in[8];
    const float* b4 = (const float*)d_in[9];
    float* out = (float*)d_out;

    unsigned char* wsb = (unsigned char*)d_ws;
    int* g_cnt = (int*)wsb;
    u16* w1p = (u16*)(wsb + WS_W1_OFF);
    u16* w2p = (u16*)(wsb + WS_W2_OFF);
    u16* w3p = (u16*)(wsb + WS_W3_OFF);
    u16* bucket = (u16*)(wsb + WS_BKT_OFF);

    hipMemsetAsync(g_cnt, 0, 8 * sizeof(int), stream);

    prep_kernel<<<PREP_BLOCKS, 256, 0, stream>>>(
        species, g_cnt, bucket, W1, W2, W3, w1p, w2p, w3p, out);

    mlp_kernel<<<MLP_BLOCKS, 64, 0, stream>>>(
        aev, w1p, w2p, w3p, b1, b2, b3, W4, b4, g_cnt, bucket, out);
}